// Round 1
// baseline (762.317 us; speedup 1.0000x reference)
//
#include <hip/hip_runtime.h>

#define QLEN 512
#define KLEN 1024
#define BATCH 8
#define HEADS 16
#define HDIM 64
#define EMBED 1024

typedef __attribute__((ext_vector_type(4))) float f32x4;
typedef __attribute__((ext_vector_type(8))) short short8;
typedef unsigned short ushort_t;
typedef unsigned char uchar_t;
typedef unsigned int uint_t;

__device__ __forceinline__ float b2f(ushort_t u) {
    union { uint_t i; float f; } c; c.i = ((uint_t)u) << 16; return c.f;
}
__device__ __forceinline__ ushort_t f2b(float x) {
    union { float f; uint_t i; } c; c.f = x;
    uint_t u = c.i;
    uint_t r = (u + 0x7FFFu + ((u >> 16) & 1u)) >> 16;
    return (ushort_t)r;
}
// load a "float" that may be stored as f32 or bf16
__device__ __forceinline__ float ldf(const void* p, int idx, int f32m) {
    if (f32m) return ((const float*)p)[idx];
    return b2f(((const ushort_t*)p)[idx]);
}

// ---------------- dtype detector ----------------
// flags[0]: 1 if float tensors are f32, 0 if bf16
// flags[1]: mask mode: 0=int32, 1=uint8, 2=bf16, 3=f32  (0/3 read as 4B word)
__global__ __launch_bounds__(256) void detect_kernel(const void* mask, const void* pad, int* flags) {
    __shared__ int cnt[4];
    int tid = threadIdx.x;
    if (tid < 4) cnt[tid] = 0;
    __syncthreads();
    const uchar_t* mb = (const uchar_t*)mask;
    const uchar_t* pb = (const uchar_t*)pad;
    int lnz1 = 0, l3f1 = 0, l3f3 = 0, lpnz = 0;
    for (int off = tid; off < 4096; off += 256) {
        uchar_t v = mb[off];
        int m4 = off & 3;
        if (m4 != 0 && v != 0) lnz1++;
        if (m4 == 1 && v == 0x3F) l3f1++;
        if (m4 == 3 && v == 0x3F) l3f3++;
        uchar_t p = pb[off];
        if (m4 == 0 && p != 0) lpnz++;
    }
    atomicAdd(&cnt[0], lnz1); atomicAdd(&cnt[1], l3f1);
    atomicAdd(&cnt[2], l3f3); atomicAdd(&cnt[3], lpnz);
    __syncthreads();
    if (tid == 0) {
        // pad values are 0.0/1.0: f32 has low byte (off%4==0) always 0; bf16 has 0x80 there for 1.0
        flags[0] = (cnt[3] == 0) ? 1 : 0;
        int mm;
        if (cnt[0] == 0) mm = 0;        // bytes 1..3 of each word all zero -> int32
        else if (cnt[1] > 16) mm = 2;   // 0x3F at odd-within-pair -> bf16 (0x3F80)
        else if (cnt[2] > 16) mm = 3;   // 0x3F only at byte 3 -> f32 (0x3F800000)
        else mm = 1;                    // uint8 bool
        flags[1] = mm;
    }
}

// ---------------- weight transpose (to bf16 W^T) ----------------
__global__ __launch_bounds__(256) void transpose_kernel(
    const void* W0, const void* W1, const void* W2, const void* W3, const void* W4,
    ushort_t* T0, ushort_t* T1, ushort_t* T2, ushort_t* T3, ushort_t* T4,
    const int* flags) {
    __shared__ float tl[32][33];
    int f32m = flags[0];
    const void* W; ushort_t* T;
    switch (blockIdx.z) {
        case 0: W = W0; T = T0; break;
        case 1: W = W1; T = T1; break;
        case 2: W = W2; T = T2; break;
        case 3: W = W3; T = T3; break;
        default: W = W4; T = T4; break;
    }
    int tx = threadIdx.x, ty = threadIdx.y;  // (32,8)
    int x = blockIdx.x * 32 + tx;
    #pragma unroll
    for (int j = 0; j < 4; ++j) {
        int row = blockIdx.y * 32 + ty + j * 8;
        tl[ty + j * 8][tx] = ldf(W, row * 1024 + x, f32m);
    }
    __syncthreads();
    #pragma unroll
    for (int j = 0; j < 4; ++j) {
        int n = blockIdx.x * 32 + ty + j * 8;
        T[n * 1024 + blockIdx.y * 32 + tx] = f2b(tl[tx][ty + j * 8]);
    }
}

// ---------------- generic projection GEMM ----------------
// C[M x 1024] = A[M x 1024] @ W  (W given transposed as BT[n][k], bf16)
// EPI 0: qU/qV (adds bq then U/V, layout (b,h,q,d));  A rows are (q*8+b)
// EPI 1: k/v proj (adds bias, layout (b,h,kk,d));     A rows are (kk*8+b)
// EPI 2: R proj (no bias, layout (h,j,d));            A rows are j
// EPI 3: out proj (adds bias, writes d_out (q,b,e), dtype per flag)
template<int EPI>
__global__ __launch_bounds__(256) void gemm_kernel(
    const void* Av, const ushort_t* BT, int M,
    const void* bias, const void* Up, const void* Vp,
    void* out0, void* out1, const int* flags, int a_mode) {
    __shared__ ushort_t As[128][40];
    __shared__ ushort_t Bs[128][40];
    int f32m = flags[0];
    int a_f32 = a_mode ? f32m : 0;
    int tid = threadIdx.x;
    int wid = tid >> 6, lane = tid & 63;
    int wr = (wid >> 1) * 64, wc = (wid & 1) * 64;
    int m0 = blockIdx.x * 128, n0 = blockIdx.y * 128;
    int srow = tid >> 1, scol = (tid & 1) * 16;

    f32x4 acc[4][4];
    #pragma unroll
    for (int m = 0; m < 4; ++m)
        #pragma unroll
        for (int n = 0; n < 4; ++n)
            acc[m][n] = (f32x4){0.f, 0.f, 0.f, 0.f};

    for (int k0 = 0; k0 < 1024; k0 += 32) {
        // stage A tile
        if (a_f32) {
            const float* Af = (const float*)Av + (m0 + srow) * 1024 + k0 + scol;
            short8 v0, v1;
            #pragma unroll
            for (int e = 0; e < 8; ++e) { v0[e] = (short)f2b(Af[e]); v1[e] = (short)f2b(Af[8 + e]); }
            *(short8*)&As[srow][scol] = v0;
            *(short8*)&As[srow][scol + 8] = v1;
        } else {
            const short8* Ab = (const short8*)((const ushort_t*)Av + (m0 + srow) * 1024 + k0 + scol);
            *(short8*)&As[srow][scol] = Ab[0];
            *(short8*)&As[srow][scol + 8] = Ab[1];
        }
        const short8* Bb = (const short8*)(BT + (n0 + srow) * 1024 + k0 + scol);
        *(short8*)&Bs[srow][scol] = Bb[0];
        *(short8*)&Bs[srow][scol + 8] = Bb[1];
        __syncthreads();

        short8 af[4], bf[4];
        #pragma unroll
        for (int m = 0; m < 4; ++m)
            af[m] = *(const short8*)&As[wr + m * 16 + (lane & 15)][(lane >> 4) * 8];
        #pragma unroll
        for (int n = 0; n < 4; ++n)
            bf[n] = *(const short8*)&Bs[wc + n * 16 + (lane & 15)][(lane >> 4) * 8];
        #pragma unroll
        for (int m = 0; m < 4; ++m)
            #pragma unroll
            for (int n = 0; n < 4; ++n)
                acc[m][n] = __builtin_amdgcn_mfma_f32_16x16x32_bf16(af[m], bf[n], acc[m][n], 0, 0, 0);
        __syncthreads();
    }

    #pragma unroll
    for (int n = 0; n < 4; ++n) {
        int gn = n0 + wc + n * 16 + (lane & 15);
        float bv_ = (EPI == 2) ? 0.f : ldf(bias, gn, f32m);
        float uu = 0.f, vv = 0.f;
        if (EPI == 0) { uu = ldf(Up, gn, f32m); vv = ldf(Vp, gn, f32m); }
        #pragma unroll
        for (int m = 0; m < 4; ++m) {
            #pragma unroll
            for (int j = 0; j < 4; ++j) {
                int gm = m0 + wr + m * 16 + (lane >> 4) * 4 + j;
                float c = acc[m][n][j] + bv_;
                if (EPI == 0) {
                    int q = gm >> 3, b = gm & 7;
                    int h = gn >> 6, d = gn & 63;
                    int idx = ((b * 16 + h) * 512 + q) * 64 + d;
                    ((ushort_t*)out0)[idx] = f2b(c + uu);
                    ((ushort_t*)out1)[idx] = f2b(c + vv);
                } else if (EPI == 1) {
                    int kk = gm >> 3, b = gm & 7;
                    int h = gn >> 6, d = gn & 63;
                    ((ushort_t*)out0)[((b * 16 + h) * 1024 + kk) * 64 + d] = f2b(c);
                } else if (EPI == 2) {
                    int h = gn >> 6, d = gn & 63;
                    ((ushort_t*)out0)[(h * 1024 + gm) * 64 + d] = f2b(c);
                } else {
                    if (f32m) ((float*)out0)[gm * 1024 + gn] = c;
                    else ((ushort_t*)out0)[gm * 1024 + gn] = f2b(c);
                }
            }
        }
    }
}

// ---------------- fused attention ----------------
// block: (q-tile of 8 rows) x (b,h);  256 threads = 4 waves
__global__ __launch_bounds__(256) void attn_kernel(
    const ushort_t* qU, const ushort_t* qV, const ushort_t* kh, const ushort_t* vh,
    const ushort_t* Rl, const void* mask, const void* pad,
    ushort_t* alpha, const int* flags) {

    __shared__ float sS[8][1028];
    __shared__ ushort_t squ[16][72];
    __shared__ ushort_t sqv[16][72];
    __shared__ float sinv[8];

    int tid = threadIdx.x;
    int wid = tid >> 6, lane = tid & 63;
    int qt = blockIdx.x;            // 0..63
    int bh = blockIdx.y;            // 0..127
    int b = bh >> 4, h = bh & 15;
    int q0 = qt * 8;
    int f32m = flags[0], mm = flags[1];

    // stage qU rows 0..7, qV rows 0..8 (zero-fill the rest of the 16-row MFMA tile)
    for (int e = tid; e < 16 * 64; e += 256) {
        int i = e >> 6, d = e & 63;
        ushort_t uq = 0, uv = 0;
        if (i < 8) uq = qU[(bh * 512 + q0 + i) * 64 + d];
        if (i < 9) { int qr = q0 + i; if (qr > 511) qr = 511; uv = qV[(bh * 512 + qr) * 64 + d]; }
        squ[i][d] = uq;
        sqv[i][d] = uv;
    }
    __syncthreads();

    // ---- content: sS[i][k] = qU[i] . K[k]  (wave w covers k in [w*256, w*256+256))
    {
        short8 a0 = *(const short8*)&squ[lane & 15][(lane >> 4) * 8];
        short8 a1 = *(const short8*)&squ[lane & 15][32 + (lane >> 4) * 8];
        f32x4 cacc[16];
        #pragma unroll
        for (int n = 0; n < 16; ++n) {
            int kcol = wid * 256 + n * 16 + (lane & 15);
            const ushort_t* kp = kh + (bh * 1024 + kcol) * 64 + (lane >> 4) * 8;
            short8 b0 = *(const short8*)kp;
            short8 b1 = *(const short8*)(kp + 32);
            f32x4 t = (f32x4){0.f, 0.f, 0.f, 0.f};
            t = __builtin_amdgcn_mfma_f32_16x16x32_bf16(a0, b0, t, 0, 0, 0);
            t = __builtin_amdgcn_mfma_f32_16x16x32_bf16(a1, b1, t, 0, 0, 0);
            cacc[n] = t;
        }
        #pragma unroll
        for (int n = 0; n < 16; ++n) {
            int kcol = wid * 256 + n * 16 + (lane & 15);
            #pragma unroll
            for (int j = 0; j < 4; ++j) {
                int row = (lane >> 4) * 4 + j;
                if (row < 8) sS[row][kcol] = cacc[n][j];
            }
        }
    }
    __syncthreads();

    // ---- position: PR[row][jc] = qV[q0+row] . R[jc], scatter-add with rel-shift
    {
        short8 a0 = *(const short8*)&sqv[lane & 15][(lane >> 4) * 8];
        short8 a1 = *(const short8*)&sqv[lane & 15][32 + (lane >> 4) * 8];
        #pragma unroll
        for (int n = 0; n < 16; ++n) {
            int jc = wid * 256 + n * 16 + (lane & 15);
            const ushort_t* rp = Rl + (h * 1024 + jc) * 64 + (lane >> 4) * 8;
            short8 b0 = *(const short8*)rp;
            short8 b1 = *(const short8*)(rp + 32);
            f32x4 t = (f32x4){0.f, 0.f, 0.f, 0.f};
            t = __builtin_amdgcn_mfma_f32_16x16x32_bf16(a0, b0, t, 0, 0, 0);
            t = __builtin_amdgcn_mfma_f32_16x16x32_bf16(a1, b1, t, 0, 0, 0);
            #pragma unroll
            for (int j = 0; j < 4; ++j) {
                int row = (lane >> 4) * 4 + j;
                float val = t[j];
                if (row < 8) {                       // normal: j = k - q + 511
                    int k1 = q0 + row + jc - 511;
                    if (k1 >= 0 && k1 < 1024) sS[row][k1] += val;
                }
                if (row >= 1 && row <= 8) {          // wrap: row q uses PR[q+1][k-q-514]
                    int k2 = q0 + row + jc + 513;
                    if (k2 < 1024) sS[row - 1][k2] += val;
                }
            }
        }
    }
    __syncthreads();

    // ---- scale + masks + softmax (wave w owns rows 2w, 2w+1)
    for (int ri = 0; ri < 2; ++ri) {
        int i = wid * 2 + ri;
        int q = q0 + i;
        float padq = ldf(pad, b * 512 + q, f32m);
        float sv[16];
        float mx = -3.0e38f;
        #pragma unroll
        for (int c = 0; c < 16; ++c) {
            int k = c * 64 + lane;
            float s = sS[i][k] * 0.03125f;
            int midx = q * 1024 + k;
            int msk;
            if (mm == 1) msk = (((const uchar_t*)mask)[midx] != 0);
            else if (mm == 2) msk = (((const ushort_t*)mask)[midx] != 0);
            else msk = (((const uint_t*)mask)[midx] != 0);
            if (k >= 512) {
                float padk = ldf(pad, b * 512 + k - 512, f32m);
                if (padq == 0.f || padk == 0.f) msk = 1;
            }
            if (msk) s = -1e20f;
            sv[c] = s;
            mx = fmaxf(mx, s);
        }
        #pragma unroll
        for (int off = 32; off > 0; off >>= 1) mx = fmaxf(mx, __shfl_xor(mx, off, 64));
        float ls = 0.f;
        #pragma unroll
        for (int c = 0; c < 16; ++c) {
            float p = __expf(sv[c] - mx);
            ls += p;
            sS[i][c * 64 + lane] = p;
        }
        #pragma unroll
        for (int off = 32; off > 0; off >>= 1) ls += __shfl_xor(ls, off, 64);
        if (lane == 0) sinv[i] = 1.0f / ls;
    }
    __syncthreads();

    // ---- PV: racc[i] = sum_k P[i][k] * V[k][d], lane owns d, wave owns k-range
    float racc[8];
    #pragma unroll
    for (int i = 0; i < 8; ++i) racc[i] = 0.f;
    int d = lane;
    for (int k4 = 0; k4 < 64; ++k4) {
        int k = wid * 256 + k4 * 4;
        const ushort_t* vp = vh + (bh * 1024 + k) * 64 + d;
        float v0 = b2f(vp[0]);
        float v1 = b2f(vp[64]);
        float v2 = b2f(vp[128]);
        float v3 = b2f(vp[192]);
        #pragma unroll
        for (int i = 0; i < 8; ++i) {
            f32x4 p4 = *(const f32x4*)&sS[i][k];
            racc[i] += p4.x * v0 + p4.y * v1 + p4.z * v2 + p4.w * v3;
        }
    }
    __syncthreads();  // all P reads done; reuse sS as reduction buffer
    float* sal = (float*)&sS[0][0];
    #pragma unroll
    for (int i = 0; i < 8; ++i) sal[(wid * 8 + i) * 64 + d] = racc[i];
    __syncthreads();
    for (int e = tid; e < 8 * 64; e += 256) {
        int i = e >> 6, dd = e & 63;
        float a = sal[i * 64 + dd] + sal[(8 + i) * 64 + dd] + sal[(16 + i) * 64 + dd] + sal[(24 + i) * 64 + dd];
        a *= sinv[i];
        alpha[((q0 + i) * 8 + b) * 1024 + h * 64 + dd] = f2b(a);
    }
}

// ---------------- launcher ----------------
extern "C" void kernel_launch(void* const* d_in, const int* in_sizes, int n_in,
                              void* d_out, int out_size, void* d_ws, size_t ws_size,
                              hipStream_t stream) {
    char* ws = (char*)d_ws;
    int* flags = (int*)ws;
    ushort_t* WqT   = (ushort_t*)(ws + 1024);
    ushort_t* WkT   = WqT + 1048576;
    ushort_t* WvT   = WkT + 1048576;
    ushort_t* WposT = WvT + 1048576;
    ushort_t* WoT   = WposT + 1048576;
    ushort_t* qUw   = WoT + 1048576;
    ushort_t* qVw   = qUw + 4194304;
    ushort_t* khw   = qVw + 4194304;
    ushort_t* vhw   = khw + 8388608;
    ushort_t* Rlw   = vhw + 8388608;
    ushort_t* alw   = Rlw + 1048576;

    detect_kernel<<<1, 256, 0, stream>>>(d_in[6], d_in[7], flags);
    transpose_kernel<<<dim3(32, 32, 5), dim3(32, 8), 0, stream>>>(
        d_in[8], d_in[10], d_in[12], d_in[14], d_in[15],
        WqT, WkT, WvT, WposT, WoT, flags);
    // q projection -> qU, qV
    gemm_kernel<0><<<dim3(32, 8), 256, 0, stream>>>(d_in[0], WqT, 4096, d_in[9], d_in[4], d_in[5], qUw, qVw, flags, 1);
    // k, v projections
    gemm_kernel<1><<<dim3(64, 8), 256, 0, stream>>>(d_in[1], WkT, 8192, d_in[11], nullptr, nullptr, khw, nullptr, flags, 1);
    gemm_kernel<1><<<dim3(64, 8), 256, 0, stream>>>(d_in[2], WvT, 8192, d_in[13], nullptr, nullptr, vhw, nullptr, flags, 1);
    // R projection
    gemm_kernel<2><<<dim3(8, 8), 256, 0, stream>>>(d_in[3], WposT, 1024, nullptr, nullptr, nullptr, Rlw, nullptr, flags, 1);
    // attention
    attn_kernel<<<dim3(64, 128), 256, 0, stream>>>(qUw, qVw, khw, vhw, Rlw, d_in[6], d_in[7], alw, flags);
    // output projection
    gemm_kernel<3><<<dim3(32, 8), 256, 0, stream>>>(alw, WoT, 4096, d_in[16], nullptr, nullptr, d_out, nullptr, flags, 0);
}

// Round 3
// 484.254 us; speedup vs baseline: 1.5742x; 1.5742x over previous
//
#include <hip/hip_runtime.h>

#define QLEN 512
#define KLEN 1024
#define BATCH 8
#define HEADS 16
#define HDIM 64
#define EMBED 1024

typedef __attribute__((ext_vector_type(4))) float f32x4;
typedef __attribute__((ext_vector_type(8))) short short8;
typedef unsigned short ushort_t;
typedef unsigned char uchar_t;
typedef unsigned int uint_t;

#define MFMA16(a, b, c) __builtin_amdgcn_mfma_f32_16x16x32_bf16((a), (b), (c), 0, 0, 0)

__device__ __forceinline__ float b2f(ushort_t u) {
    union { uint_t i; float f; } c; c.i = ((uint_t)u) << 16; return c.f;
}
__device__ __forceinline__ ushort_t f2b(float x) {
    union { float f; uint_t i; } c; c.f = x;
    uint_t u = c.i;
    uint_t r = (u + 0x7FFFu + ((u >> 16) & 1u)) >> 16;
    return (ushort_t)r;
}
__device__ __forceinline__ uint_t pk2(float lo, float hi) {
    return (uint_t)f2b(lo) | ((uint_t)f2b(hi) << 16);
}
// load a "float" that may be stored as f32 or bf16
__device__ __forceinline__ float ldf(const void* p, int idx, int f32m) {
    if (f32m) return ((const float*)p)[idx];
    return b2f(((const ushort_t*)p)[idx]);
}

typedef const __attribute__((address_space(1))) void async_src_t;
typedef __attribute__((address_space(3))) void async_dst_t;

// ---------------- dtype detector ----------------
// flags[0]: 1 if float tensors are f32, 0 if bf16
// flags[1]: mask mode: 0=int32, 1=uint8, 2=bf16, 3=f32
__global__ __launch_bounds__(256) void detect_kernel(const void* mask, const void* pad, int* flags) {
    __shared__ int cnt[4];
    int tid = threadIdx.x;
    if (tid < 4) cnt[tid] = 0;
    __syncthreads();
    const uchar_t* mb = (const uchar_t*)mask;
    const uchar_t* pb = (const uchar_t*)pad;
    int lnz1 = 0, l3f1 = 0, l3f3 = 0, lpnz = 0;
    for (int off = tid; off < 4096; off += 256) {
        uchar_t v = mb[off];
        int m4 = off & 3;
        if (m4 != 0 && v != 0) lnz1++;
        if (m4 == 1 && v == 0x3F) l3f1++;
        if (m4 == 3 && v == 0x3F) l3f3++;
        uchar_t p = pb[off];
        if (m4 == 0 && p != 0) lpnz++;
    }
    atomicAdd(&cnt[0], lnz1); atomicAdd(&cnt[1], l3f1);
    atomicAdd(&cnt[2], l3f3); atomicAdd(&cnt[3], lpnz);
    __syncthreads();
    if (tid == 0) {
        flags[0] = (cnt[3] == 0) ? 1 : 0;
        int mm;
        if (cnt[0] == 0) mm = 0;
        else if (cnt[1] > 16) mm = 2;
        else if (cnt[2] > 16) mm = 3;
        else mm = 1;
        flags[1] = mm;
    }
}

// ---------------- weight transpose (to bf16 W^T) ----------------
__global__ __launch_bounds__(256) void transpose_kernel(
    const void* W0, const void* W1, const void* W2, const void* W3, const void* W4,
    ushort_t* T0, ushort_t* T1, ushort_t* T2, ushort_t* T3, ushort_t* T4,
    const int* flags) {
    __shared__ float tl[32][33];
    int f32m = flags[0];
    const void* W; ushort_t* T;
    switch (blockIdx.z) {
        case 0: W = W0; T = T0; break;
        case 1: W = W1; T = T1; break;
        case 2: W = W2; T = T2; break;
        case 3: W = W3; T = T3; break;
        default: W = W4; T = T4; break;
    }
    int tx = threadIdx.x, ty = threadIdx.y;  // (32,8)
    int x = blockIdx.x * 32 + tx;
    #pragma unroll
    for (int j = 0; j < 4; ++j) {
        int row = blockIdx.y * 32 + ty + j * 8;
        tl[ty + j * 8][tx] = ldf(W, row * 1024 + x, f32m);
    }
    __syncthreads();
    #pragma unroll
    for (int j = 0; j < 4; ++j) {
        int n = blockIdx.x * 32 + ty + j * 8;
        T[n * 1024 + blockIdx.y * 32 + tx] = f2b(tl[tx][ty + j * 8]);
    }
}

// ---------------- V transpose: vh[bh][k][d] -> vT[bh][d][k] ----------------
__global__ __launch_bounds__(256) void vtrans_kernel(const ushort_t* __restrict__ vh,
                                                     ushort_t* __restrict__ vT) {
    __shared__ ushort_t t[64][68];
    int bh = blockIdx.y;
    int k0 = blockIdx.x * 64;
    int tid = threadIdx.x;
    int r = tid >> 2, c0 = (tid & 3) * 16;
    const short8* src = (const short8*)&vh[((size_t)bh * 1024 + k0 + r) * 64 + c0];
    *(short8*)&t[r][c0] = src[0];
    *(short8*)&t[r][c0 + 8] = src[1];
    __syncthreads();
    ushort_t tmp[16];
    #pragma unroll
    for (int j = 0; j < 16; ++j) tmp[j] = t[c0 + j][r];
    short8* dst = (short8*)&vT[((size_t)bh * 64 + r) * 1024 + k0 + c0];
    dst[0] = *(short8*)&tmp[0];
    dst[1] = *(short8*)&tmp[8];
}

// ---------------- projection GEMM (m97-style: global_load_lds, linear LDS) ----------------
// C[M x 1024] = A[M x 1024] @ W  (W transposed: BT[n][k], bf16)
// EPI 0: qU/qV (adds bq then U/V, layout (b,h,q,d))
// EPI 1: k/v proj (adds bias, layout (b,h,kk,d))
// EPI 2: R proj (no bias, layout (h,j,d))
// EPI 3: out proj (adds bias, writes d_out (q,b,e), dtype per flag)
template<int EPI>
__global__ __launch_bounds__(256) void gemm_kernel(
    const void* Av, const ushort_t* BT, int M,
    const void* bias, const void* Up, const void* Vp,
    void* out0, void* out1, const int* flags, int a_mode) {
    __shared__ ushort_t As[4096];
    __shared__ ushort_t Bs[4096];
    const int f32m = flags[0];
    const int a_f32 = a_mode ? f32m : 0;
    const int tid = threadIdx.x;
    const int wid = tid >> 6, lane = tid & 63;
    const int wr = (wid >> 1) * 64, wc = (wid & 1) * 64;
    const int m0 = blockIdx.x * 128, n0 = blockIdx.y * 128;
    const int ch0 = wid * 2;
    const int lrow = lane >> 2, lcol = (lane & 3) * 8;

    f32x4 acc[4][4];
    #pragma unroll
    for (int m = 0; m < 4; ++m)
        #pragma unroll
        for (int n = 0; n < 4; ++n)
            acc[m][n] = (f32x4){0.f, 0.f, 0.f, 0.f};

    for (int k0 = 0; k0 < 1024; k0 += 32) {
        if (a_f32) {
            const float* Af = (const float*)Av + (size_t)(m0 + (tid >> 1)) * 1024 + k0 + (tid & 1) * 16;
            ushort_t* dst = &As[(tid >> 1) * 32 + (tid & 1) * 16];
            #pragma unroll
            for (int e = 0; e < 16; ++e) dst[e] = f2b(Af[e]);
        } else {
            #pragma unroll
            for (int t = 0; t < 2; ++t) {
                int ch = ch0 + t;
                const ushort_t* ga = (const ushort_t*)Av + (size_t)(m0 + ch * 16 + lrow) * 1024 + k0 + lcol;
                __builtin_amdgcn_global_load_lds((async_src_t*)ga, (async_dst_t*)&As[ch * 512], 16, 0, 0);
            }
        }
        #pragma unroll
        for (int t = 0; t < 2; ++t) {
            int ch = ch0 + t;
            const ushort_t* gb = BT + (size_t)(n0 + ch * 16 + lrow) * 1024 + k0 + lcol;
            __builtin_amdgcn_global_load_lds((async_src_t*)gb, (async_dst_t*)&Bs[ch * 512], 16, 0, 0);
        }
        __syncthreads();

        short8 af[4], bf[4];
        #pragma unroll
        for (int m = 0; m < 4; ++m)
            af[m] = *(const short8*)&As[(wr + m * 16 + (lane & 15)) * 32 + (lane >> 4) * 8];
        #pragma unroll
        for (int n = 0; n < 4; ++n)
            bf[n] = *(const short8*)&Bs[(wc + n * 16 + (lane & 15)) * 32 + (lane >> 4) * 8];
        #pragma unroll
        for (int m = 0; m < 4; ++m)
            #pragma unroll
            for (int n = 0; n < 4; ++n)
                acc[m][n] = MFMA16(af[m], bf[n], acc[m][n]);
        __syncthreads();
    }

    #pragma unroll
    for (int n = 0; n < 4; ++n) {
        int gn = n0 + wc + n * 16 + (lane & 15);
        float bv_ = (EPI == 2) ? 0.f : ldf(bias, gn, f32m);
        float uu = 0.f, vv = 0.f;
        if (EPI == 0) { uu = ldf(Up, gn, f32m); vv = ldf(Vp, gn, f32m); }
        #pragma unroll
        for (int m = 0; m < 4; ++m) {
            #pragma unroll
            for (int j = 0; j < 4; ++j) {
                int gm = m0 + wr + m * 16 + (lane >> 4) * 4 + j;
                float c = acc[m][n][j] + bv_;
                if (EPI == 0) {
                    int q = gm >> 3, b = gm & 7;
                    int h = gn >> 6, d = gn & 63;
                    int idx = ((b * 16 + h) * 512 + q) * 64 + d;
                    ((ushort_t*)out0)[idx] = f2b(c + uu);
                    ((ushort_t*)out1)[idx] = f2b(c + vv);
                } else if (EPI == 1) {
                    int kk = gm >> 3, b = gm & 7;
                    int h = gn >> 6, d = gn & 63;
                    ((ushort_t*)out0)[((b * 16 + h) * 1024 + kk) * 64 + d] = f2b(c);
                } else if (EPI == 2) {
                    int h = gn >> 6, d = gn & 63;
                    ((ushort_t*)out0)[(h * 1024 + gm) * 64 + d] = f2b(c);
                } else {
                    if (f32m) ((float*)out0)[gm * 1024 + gn] = c;
                    else ((ushort_t*)out0)[gm * 1024 + gn] = f2b(c);
                }
            }
        }
    }
}

// ---------------- fused attention (S^T layout, MFMA PV) ----------------
// block: 16 q-rows x one (b,h); 4 waves, wave w owns k in [w*256, w*256+256)
// Lane: c = lane&15 = q-column, g = lane>>4. S^T C-layout: col=c(q), row=k-local.
__global__ __launch_bounds__(256, 2) void attn_kernel(
    const ushort_t* __restrict__ qU, const ushort_t* __restrict__ qV,
    const ushort_t* __restrict__ kh, const ushort_t* __restrict__ vT,
    const ushort_t* __restrict__ Rl, const void* __restrict__ mask,
    const void* __restrict__ pad, ushort_t* __restrict__ alpha, const int* flags) {

    __shared__ float sPR[17 * 1028];   // PR[q0..q0+16][j], stride 1028
    __shared__ float spad[512];
    __shared__ float sred[2][4][16];
    __shared__ float ssinv[16];

    const int tid = threadIdx.x;
    const int wid = tid >> 6, lane = tid & 63;
    const int g = lane >> 4, c = lane & 15;
    const int q0 = blockIdx.x * 16;
    const int bh = blockIdx.y;
    const int b = bh >> 4, h = bh & 15;
    const int f32m = flags[0], mm = flags[1];
    const int kbase = wid * 256;

    for (int e = tid; e < 512; e += 256) spad[e] = ldf(pad, b * 512 + e, f32m);

    // B-fragments (col = q): qU rows q0+c ; qV rows q0+c and q0+16+c (clamped)
    const ushort_t* qup = qU + ((size_t)bh * 512 + q0 + c) * 64 + g * 8;
    short8 bu0 = *(const short8*)qup;
    short8 bu1 = *(const short8*)(qup + 32);
    const ushort_t* qvap = qV + ((size_t)bh * 512 + q0 + c) * 64 + g * 8;
    short8 bva0 = *(const short8*)qvap;
    short8 bva1 = *(const short8*)(qvap + 32);
    int qvbq = q0 + 16 + c; if (qvbq > 511) qvbq = 511;
    const ushort_t* qvbp = qV + ((size_t)bh * 512 + qvbq) * 64 + g * 8;
    short8 bvb0 = *(const short8*)qvbp;
    short8 bvb1 = *(const short8*)(qvbp + 32);

    // ---- position: PR^T[j][q] = R[j] . qV[q];  write PR[q][j] (f32) to LDS
    #pragma unroll
    for (int m = 0; m < 16; ++m) {
        const ushort_t* rp = Rl + ((size_t)h * 1024 + kbase + m * 16 + c) * 64 + g * 8;
        short8 ra0 = *(const short8*)rp;
        short8 ra1 = *(const short8*)(rp + 32);
        f32x4 p0 = (f32x4){0.f, 0.f, 0.f, 0.f};
        p0 = MFMA16(ra0, bva0, p0);
        p0 = MFMA16(ra1, bva1, p0);
        f32x4 p1 = (f32x4){0.f, 0.f, 0.f, 0.f};
        p1 = MFMA16(ra0, bvb0, p1);
        p1 = MFMA16(ra1, bvb1, p1);
        *(f32x4*)&sPR[c * 1028 + kbase + m * 16 + g * 4] = p0;
        if (c == 0) *(f32x4*)&sPR[16 * 1028 + kbase + m * 16 + g * 4] = p1;
    }

    // ---- content: S^T[k][q] = K[k] . qU[q]
    f32x4 acc[16];
    #pragma unroll
    for (int m = 0; m < 16; ++m) {
        const ushort_t* kp = kh + ((size_t)bh * 1024 + kbase + m * 16 + c) * 64 + g * 8;
        short8 ka0 = *(const short8*)kp;
        short8 ka1 = *(const short8*)(kp + 32);
        f32x4 t = (f32x4){0.f, 0.f, 0.f, 0.f};
        t = MFMA16(ka0, bu0, t);
        t = MFMA16(ka1, bu1, t);
        acc[m] = t;
    }
    __syncthreads();

    // ---- score: add rel-shifted position (LDS gather), scale, masks
    const int q = q0 + c;
    const float padq = spad[q];
    float mx = -3.0e38f;
    #pragma unroll
    for (int m = 0; m < 16; ++m) {
        int k0e = kbase + m * 16 + g * 4;
        uint_t mb[4];
        if (mm == 1) {
            uint_t w = *(const uint_t*)((const uchar_t*)mask + (size_t)q * 1024 + k0e);
            mb[0] = w & 0xFFu; mb[1] = w & 0xFF00u; mb[2] = w & 0xFF0000u; mb[3] = w & 0xFF000000u;
        } else if (mm == 2) {
            uint2 w = *(const uint2*)((const ushort_t*)mask + (size_t)q * 1024 + k0e);
            mb[0] = w.x & 0xFFFFu; mb[1] = w.x >> 16; mb[2] = w.y & 0xFFFFu; mb[3] = w.y >> 16;
        } else {
            uint4 w = *(const uint4*)((const uint_t*)mask + (size_t)q * 1024 + k0e);
            mb[0] = w.x; mb[1] = w.y; mb[2] = w.z; mb[3] = w.w;
        }
        #pragma unroll
        for (int jj = 0; jj < 4; ++jj) {
            int k = k0e + jj;
            int delta = k - q;
            int wrap = (delta > 512) ? 1 : 0;
            int j = wrap ? (delta - 514) : (delta + 511);
            float pos = sPR[(c + wrap) * 1028 + (j < 0 ? 0 : j)];
            if (delta == 513) pos = 0.f;
            float s = (acc[m][jj] + pos) * 0.03125f;
            bool dead = (mb[jj] != 0);
            if (k >= 512) {
                float padk = spad[k - 512];
                if (padq == 0.f || padk == 0.f) dead = true;
            }
            if (dead) s = -1e20f;
            acc[m][jj] = s;
            mx = fmaxf(mx, s);
        }
    }
    // row-max: lanes sharing q are xor-16/32 apart
    mx = fmaxf(mx, __shfl_xor(mx, 16, 64));
    mx = fmaxf(mx, __shfl_xor(mx, 32, 64));
    if (lane < 16) sred[0][wid][c] = mx;
    __syncthreads();
    mx = fmaxf(fmaxf(sred[0][0][c], sred[0][1][c]), fmaxf(sred[0][2][c], sred[0][3][c]));

    float ls = 0.f;
    #pragma unroll
    for (int m = 0; m < 16; ++m) {
        #pragma unroll
        for (int jj = 0; jj < 4; ++jj) {
            float p = __expf(acc[m][jj] - mx);
            acc[m][jj] = p;
            ls += p;
        }
    }
    ls += __shfl_xor(ls, 16, 64);
    ls += __shfl_xor(ls, 32, 64);
    if (lane < 16) sred[1][wid][c] = ls;
    __syncthreads();
    ls = (sred[1][0][c] + sred[1][1][c]) + (sred[1][2][c] + sred[1][3][c]);
    if (wid == 0 && lane < 16) ssinv[c] = 1.0f / ls;

    // ---- PV: O^T[d][q] = sum_k V^T[d][k] P^T[k][q], MFMA with in-register P exchange
    f32x4 oacc[4];
    #pragma unroll
    for (int dm = 0; dm < 4; ++dm) oacc[dm] = (f32x4){0.f, 0.f, 0.f, 0.f};
    const int srcA = c + ((g & 1) ? 32 : 0);
    const int srcB = srcA + 16;
    #pragma unroll
    for (int ch = 0; ch < 8; ++ch) {
        const int mA = ch * 2, mB = mA + 1;
        uint_t u00 = pk2(acc[mA][0], acc[mA][1]);
        uint_t u10 = pk2(acc[mA][2], acc[mA][3]);
        uint_t u01 = pk2(acc[mB][0], acc[mB][1]);
        uint_t u11 = pk2(acc[mB][2], acc[mB][3]);
        uint_t r0 = (uint_t)__shfl((int)u00, srcA, 64);
        uint_t r1 = (uint_t)__shfl((int)u10, srcA, 64);
        uint_t r2 = (uint_t)__shfl((int)u00, srcB, 64);
        uint_t r3 = (uint_t)__shfl((int)u10, srcB, 64);
        uint_t s0 = (uint_t)__shfl((int)u01, srcA, 64);
        uint_t s1 = (uint_t)__shfl((int)u11, srcA, 64);
        uint_t s2 = (uint_t)__shfl((int)u01, srcB, 64);
        uint_t s3 = (uint_t)__shfl((int)u11, srcB, 64);
        union { uint_t u[4]; short8 s8; } pb;
        bool lo = (g < 2);
        pb.u[0] = lo ? r0 : s0;
        pb.u[1] = lo ? r1 : s1;
        pb.u[2] = lo ? r2 : s2;
        pb.u[3] = lo ? r3 : s3;
        #pragma unroll
        for (int dm = 0; dm < 4; ++dm) {
            const ushort_t* vp = vT + ((size_t)bh * 64 + dm * 16 + c) * 1024 + kbase + ch * 32 + g * 8;
            short8 va = *(const short8*)vp;
            oacc[dm] = MFMA16(va, pb.s8, oacc[dm]);
        }
    }

    // cross-wave O reduction (reuse sPR region; all PR reads completed pre-barrier)
    float* sO = sPR;
    #pragma unroll
    for (int dm = 0; dm < 4; ++dm)
        #pragma unroll
        for (int jj = 0; jj < 4; ++jj)
            sO[wid * 1152 + (dm * 16 + g * 4 + jj) * 18 + c] = oacc[dm][jj];
    __syncthreads();
    for (int e = tid; e < 1024; e += 256) {
        int d = e & 63, qq = e >> 6;
        float v = (sO[d * 18 + qq] + sO[1152 + d * 18 + qq]) +
                  (sO[2304 + d * 18 + qq] + sO[3456 + d * 18 + qq]);
        v *= ssinv[qq];
        alpha[((size_t)(q0 + qq) * 8 + b) * 1024 + h * 64 + d] = f2b(v);
    }
}

// ---------------- launcher ----------------
extern "C" void kernel_launch(void* const* d_in, const int* in_sizes, int n_in,
                              void* d_out, int out_size, void* d_ws, size_t ws_size,
                              hipStream_t stream) {
    char* ws = (char*)d_ws;
    int* flags = (int*)ws;
    ushort_t* WqT   = (ushort_t*)(ws + 1024);
    ushort_t* WkT   = WqT + 1048576;
    ushort_t* WvT   = WkT + 1048576;
    ushort_t* WposT = WvT + 1048576;
    ushort_t* WoT   = WposT + 1048576;
    ushort_t* qUw   = WoT + 1048576;
    ushort_t* qVw   = qUw + 4194304;
    ushort_t* khw   = qVw + 4194304;
    ushort_t* vhw   = khw + 8388608;
    ushort_t* vTw   = vhw + 8388608;
    ushort_t* Rlw   = vTw + 8388608;
    ushort_t* alw   = Rlw + 1048576;

    detect_kernel<<<1, 256, 0, stream>>>(d_in[6], d_in[7], flags);
    transpose_kernel<<<dim3(32, 32, 5), dim3(32, 8), 0, stream>>>(
        d_in[8], d_in[10], d_in[12], d_in[14], d_in[15],
        WqT, WkT, WvT, WposT, WoT, flags);
    // q projection -> qU, qV
    gemm_kernel<0><<<dim3(32, 8), 256, 0, stream>>>(d_in[0], WqT, 4096, d_in[9], d_in[4], d_in[5], qUw, qVw, flags, 1);
    // k, v projections
    gemm_kernel<1><<<dim3(64, 8), 256, 0, stream>>>(d_in[1], WkT, 8192, d_in[11], nullptr, nullptr, khw, nullptr, flags, 1);
    gemm_kernel<1><<<dim3(64, 8), 256, 0, stream>>>(d_in[2], WvT, 8192, d_in[13], nullptr, nullptr, vhw, nullptr, flags, 1);
    // R projection
    gemm_kernel<2><<<dim3(8, 8), 256, 0, stream>>>(d_in[3], WposT, 1024, nullptr, nullptr, nullptr, Rlw, nullptr, flags, 1);
    // V transpose for PV A-operand
    vtrans_kernel<<<dim3(16, 128), 256, 0, stream>>>(vhw, vTw);
    // fused attention
    attn_kernel<<<dim3(32, 128), 256, 0, stream>>>(qUw, qVw, khw, vTw, Rlw, d_in[6], d_in[7], alw, flags);
    // output projection
    gemm_kernel<3><<<dim3(32, 8), 256, 0, stream>>>(alw, WoT, 4096, d_in[16], nullptr, nullptr, d_out, nullptr, flags, 0);
}

// Round 6
// 482.956 us; speedup vs baseline: 1.5784x; 1.0027x over previous
//
#include <hip/hip_runtime.h>

#define QLEN 512
#define KLEN 1024
#define BATCH 8
#define HEADS 16
#define HDIM 64
#define EMBED 1024

typedef __attribute__((ext_vector_type(4))) float f32x4;
typedef __attribute__((ext_vector_type(8))) short short8;
typedef unsigned short ushort_t;
typedef unsigned char uchar_t;
typedef unsigned int uint_t;

#define MFMA16(a, b, c) __builtin_amdgcn_mfma_f32_16x16x32_bf16((a), (b), (c), 0, 0, 0)

__device__ __forceinline__ float b2f(ushort_t u) {
    union { uint_t i; float f; } c; c.i = ((uint_t)u) << 16; return c.f;
}
__device__ __forceinline__ ushort_t f2b(float x) {
    union { float f; uint_t i; } c; c.f = x;
    uint_t u = c.i;
    uint_t r = (u + 0x7FFFu + ((u >> 16) & 1u)) >> 16;
    return (ushort_t)r;
}
__device__ __forceinline__ uint_t pk2(float lo, float hi) {
    return (uint_t)f2b(lo) | ((uint_t)f2b(hi) << 16);
}
// load a "float" that may be stored as f32 or bf16
__device__ __forceinline__ float ldf(const void* p, int idx, int f32m) {
    if (f32m) return ((const float*)p)[idx];
    return b2f(((const ushort_t*)p)[idx]);
}

typedef const __attribute__((address_space(1))) void async_src_t;
typedef __attribute__((address_space(3))) void async_dst_t;

// ---------------- dtype detector ----------------
// flags[0]: 1 if float tensors are f32, 0 if bf16
// flags[1]: mask mode: 0=int32, 1=uint8, 2=bf16, 3=f32
__global__ __launch_bounds__(256) void detect_kernel(const void* mask, const void* pad, int* flags) {
    __shared__ int cnt[4];
    int tid = threadIdx.x;
    if (tid < 4) cnt[tid] = 0;
    __syncthreads();
    const uchar_t* mb = (const uchar_t*)mask;
    const uchar_t* pb = (const uchar_t*)pad;
    int lnz1 = 0, l3f1 = 0, l3f3 = 0, lpnz = 0;
    for (int off = tid; off < 4096; off += 256) {
        uchar_t v = mb[off];
        int m4 = off & 3;
        if (m4 != 0 && v != 0) lnz1++;
        if (m4 == 1 && v == 0x3F) l3f1++;
        if (m4 == 3 && v == 0x3F) l3f3++;
        uchar_t p = pb[off];
        if (m4 == 0 && p != 0) lpnz++;
    }
    atomicAdd(&cnt[0], lnz1); atomicAdd(&cnt[1], l3f1);
    atomicAdd(&cnt[2], l3f3); atomicAdd(&cnt[3], lpnz);
    __syncthreads();
    if (tid == 0) {
        flags[0] = (cnt[3] == 0) ? 1 : 0;
        int mm;
        if (cnt[0] == 0) mm = 0;
        else if (cnt[1] > 16) mm = 2;
        else if (cnt[2] > 16) mm = 3;
        else mm = 1;
        flags[1] = mm;
    }
}

// ---------------- weight transpose (to bf16 W^T) ----------------
__global__ __launch_bounds__(256) void transpose_kernel(
    const void* W0, const void* W1, const void* W2, const void* W3, const void* W4,
    ushort_t* T0, ushort_t* T1, ushort_t* T2, ushort_t* T3, ushort_t* T4,
    const int* flags) {
    __shared__ float tl[32][33];
    int f32m = flags[0];
    const void* W; ushort_t* T;
    switch (blockIdx.z) {
        case 0: W = W0; T = T0; break;
        case 1: W = W1; T = T1; break;
        case 2: W = W2; T = T2; break;
        case 3: W = W3; T = T3; break;
        default: W = W4; T = T4; break;
    }
    int tx = threadIdx.x, ty = threadIdx.y;  // (32,8)
    int x = blockIdx.x * 32 + tx;
    #pragma unroll
    for (int j = 0; j < 4; ++j) {
        int row = blockIdx.y * 32 + ty + j * 8;
        tl[ty + j * 8][tx] = ldf(W, row * 1024 + x, f32m);
    }
    __syncthreads();
    #pragma unroll
    for (int j = 0; j < 4; ++j) {
        int n = blockIdx.x * 32 + ty + j * 8;
        T[n * 1024 + blockIdx.y * 32 + tx] = f2b(tl[tx][ty + j * 8]);
    }
}

// ---------------- V transpose: vh[bh][k][d] -> vT[bh][d][k] ----------------
__global__ __launch_bounds__(256) void vtrans_kernel(const ushort_t* __restrict__ vh,
                                                     ushort_t* __restrict__ vT) {
    __shared__ ushort_t t[64][68];
    int bh = blockIdx.y;
    int k0 = blockIdx.x * 64;
    int tid = threadIdx.x;
    int r = tid >> 2, c0 = (tid & 3) * 16;
    const short8* src = (const short8*)&vh[((size_t)bh * 1024 + k0 + r) * 64 + c0];
    *(short8*)&t[r][c0] = src[0];
    *(short8*)&t[r][c0 + 8] = src[1];
    __syncthreads();
    ushort_t tmp[16];
    #pragma unroll
    for (int j = 0; j < 16; ++j) tmp[j] = t[c0 + j][r];
    short8* dst = (short8*)&vT[((size_t)bh * 64 + r) * 1024 + k0 + c0];
    dst[0] = *(short8*)&tmp[0];
    dst[1] = *(short8*)&tmp[8];
}

// ---------------- projection GEMM (global_load_lds, linear LDS) ----------------
// EPI 0: qU/qV (adds bq then U/V, layout (b,h,q,d))
// EPI 1: k/v proj (adds bias, layout (b,h,kk,d))
// EPI 2: R proj (no bias, layout (h,j,d))
// EPI 3: out proj (adds bias, writes d_out (q,b,e), dtype per flag)
template<int EPI>
__global__ __launch_bounds__(256) void gemm_kernel(
    const void* Av, const ushort_t* BT, int M,
    const void* bias, const void* Up, const void* Vp,
    void* out0, void* out1, const int* flags, int a_mode) {
    __shared__ ushort_t As[4096];
    __shared__ ushort_t Bs[4096];
    const int f32m = flags[0];
    const int a_f32 = a_mode ? f32m : 0;
    const int tid = threadIdx.x;
    const int wid = tid >> 6, lane = tid & 63;
    const int wr = (wid >> 1) * 64, wc = (wid & 1) * 64;
    const int m0 = blockIdx.x * 128, n0 = blockIdx.y * 128;
    const int ch0 = wid * 2;
    const int lrow = lane >> 2, lcol = (lane & 3) * 8;

    f32x4 acc[4][4];
    #pragma unroll
    for (int m = 0; m < 4; ++m)
        #pragma unroll
        for (int n = 0; n < 4; ++n)
            acc[m][n] = (f32x4){0.f, 0.f, 0.f, 0.f};

    for (int k0 = 0; k0 < 1024; k0 += 32) {
        if (a_f32) {
            const float* Af = (const float*)Av + (size_t)(m0 + (tid >> 1)) * 1024 + k0 + (tid & 1) * 16;
            ushort_t* dst = &As[(tid >> 1) * 32 + (tid & 1) * 16];
            #pragma unroll
            for (int e = 0; e < 16; ++e) dst[e] = f2b(Af[e]);
        } else {
            #pragma unroll
            for (int t = 0; t < 2; ++t) {
                int ch = ch0 + t;
                const ushort_t* ga = (const ushort_t*)Av + (size_t)(m0 + ch * 16 + lrow) * 1024 + k0 + lcol;
                __builtin_amdgcn_global_load_lds((async_src_t*)ga, (async_dst_t*)&As[ch * 512], 16, 0, 0);
            }
        }
        #pragma unroll
        for (int t = 0; t < 2; ++t) {
            int ch = ch0 + t;
            const ushort_t* gb = BT + (size_t)(n0 + ch * 16 + lrow) * 1024 + k0 + lcol;
            __builtin_amdgcn_global_load_lds((async_src_t*)gb, (async_dst_t*)&Bs[ch * 512], 16, 0, 0);
        }
        __syncthreads();

        short8 af[4], bf[4];
        #pragma unroll
        for (int m = 0; m < 4; ++m)
            af[m] = *(const short8*)&As[(wr + m * 16 + (lane & 15)) * 32 + (lane >> 4) * 8];
        #pragma unroll
        for (int n = 0; n < 4; ++n)
            bf[n] = *(const short8*)&Bs[(wc + n * 16 + (lane & 15)) * 32 + (lane >> 4) * 8];
        #pragma unroll
        for (int m = 0; m < 4; ++m)
            #pragma unroll
            for (int n = 0; n < 4; ++n)
                acc[m][n] = MFMA16(af[m], bf[n], acc[m][n]);
        __syncthreads();
    }

    #pragma unroll
    for (int n = 0; n < 4; ++n) {
        int gn = n0 + wc + n * 16 + (lane & 15);
        float bv_ = (EPI == 2) ? 0.f : ldf(bias, gn, f32m);
        float uu = 0.f, vv = 0.f;
        if (EPI == 0) { uu = ldf(Up, gn, f32m); vv = ldf(Vp, gn, f32m); }
        #pragma unroll
        for (int m = 0; m < 4; ++m) {
            #pragma unroll
            for (int j = 0; j < 4; ++j) {
                int gm = m0 + wr + m * 16 + (lane >> 4) * 4 + j;
                float c = acc[m][n][j] + bv_;
                if (EPI == 0) {
                    int q = gm >> 3, b = gm & 7;
                    int h = gn >> 6, d = gn & 63;
                    int idx = ((b * 16 + h) * 512 + q) * 64 + d;
                    ((ushort_t*)out0)[idx] = f2b(c + uu);
                    ((ushort_t*)out1)[idx] = f2b(c + vv);
                } else if (EPI == 1) {
                    int kk = gm >> 3, b = gm & 7;
                    int h = gn >> 6, d = gn & 63;
                    ((ushort_t*)out0)[((b * 16 + h) * 1024 + kk) * 64 + d] = f2b(c);
                } else if (EPI == 2) {
                    int h = gn >> 6, d = gn & 63;
                    ((ushort_t*)out0)[(h * 1024 + gm) * 64 + d] = f2b(c);
                } else {
                    if (f32m) ((float*)out0)[gm * 1024 + gn] = c;
                    else ((ushort_t*)out0)[gm * 1024 + gn] = f2b(c);
                }
            }
        }
    }
}

// ---------------- fused attention (S^T layout, MFMA PV, bf16 PR tile) ----------------
// block: 16 q-rows x one (b,h); 4 waves, wave w owns k in [w*256, w*256+256)
// Lane: c = lane&15 = q-column, g = lane>>4. S^T C-layout: col=c(q), row=k-local.
__global__ __launch_bounds__(256, 2) void attn_kernel(
    const ushort_t* __restrict__ qU, const ushort_t* __restrict__ qV,
    const ushort_t* __restrict__ kh, const ushort_t* __restrict__ vT,
    const ushort_t* __restrict__ Rl, const void* __restrict__ mask,
    const void* __restrict__ pad, ushort_t* __restrict__ alpha, const int* flags) {

    __shared__ __align__(16) ushort_t sPRu[17 * 1040];   // PR rows q0..q0+16, bf16, stride 1040
    __shared__ float spad[512];
    __shared__ float sred[2][4][16];
    __shared__ float ssinv[16];

    const int tid = threadIdx.x;
    const int wid = tid >> 6, lane = tid & 63;
    const int g = lane >> 4, c = lane & 15;
    const int q0 = blockIdx.x * 16;
    const int bh = blockIdx.y;
    const int b = bh >> 4, h = bh & 15;
    const int f32m = flags[0], mm = flags[1];
    const int kbase = wid * 256;

    for (int e = tid; e < 512; e += 256) spad[e] = ldf(pad, b * 512 + e, f32m);

    // B-fragments (col = q): qU rows q0+c ; qV rows q0+c and q0+16+c (clamped)
    const ushort_t* qup = qU + ((size_t)bh * 512 + q0 + c) * 64 + g * 8;
    short8 bu0 = *(const short8*)qup;
    short8 bu1 = *(const short8*)(qup + 32);
    const ushort_t* qvap = qV + ((size_t)bh * 512 + q0 + c) * 64 + g * 8;
    short8 bva0 = *(const short8*)qvap;
    short8 bva1 = *(const short8*)(qvap + 32);
    int qvbq = q0 + 16 + c; if (qvbq > 511) qvbq = 511;
    const ushort_t* qvbp = qV + ((size_t)bh * 512 + qvbq) * 64 + g * 8;
    short8 bvb0 = *(const short8*)qvbp;
    short8 bvb1 = *(const short8*)(qvbp + 32);

    // ---- position: PR^T[j][q] = R[j] . qV[q];  write PR[q][j] (bf16) to LDS
    #pragma unroll
    for (int m = 0; m < 16; ++m) {
        const ushort_t* rp = Rl + ((size_t)h * 1024 + kbase + m * 16 + c) * 64 + g * 8;
        short8 ra0 = *(const short8*)rp;
        short8 ra1 = *(const short8*)(rp + 32);
        f32x4 p0 = (f32x4){0.f, 0.f, 0.f, 0.f};
        p0 = MFMA16(ra0, bva0, p0);
        p0 = MFMA16(ra1, bva1, p0);
        f32x4 p1 = (f32x4){0.f, 0.f, 0.f, 0.f};
        p1 = MFMA16(ra0, bvb0, p1);
        p1 = MFMA16(ra1, bvb1, p1);
        uint2 w;
        w.x = pk2(p0[0], p0[1]);
        w.y = pk2(p0[2], p0[3]);
        *(uint2*)&sPRu[c * 1040 + kbase + m * 16 + g * 4] = w;
        if (c == 0) {
            uint2 x;
            x.x = pk2(p1[0], p1[1]);
            x.y = pk2(p1[2], p1[3]);
            *(uint2*)&sPRu[16 * 1040 + kbase + m * 16 + g * 4] = x;
        }
    }

    // ---- content: S^T[k][q] = K[k] . qU[q]
    f32x4 acc[16];
    #pragma unroll
    for (int m = 0; m < 16; ++m) {
        const ushort_t* kp = kh + ((size_t)bh * 1024 + kbase + m * 16 + c) * 64 + g * 8;
        short8 ka0 = *(const short8*)kp;
        short8 ka1 = *(const short8*)(kp + 32);
        f32x4 t = (f32x4){0.f, 0.f, 0.f, 0.f};
        t = MFMA16(ka0, bu0, t);
        t = MFMA16(ka1, bu1, t);
        acc[m] = t;
    }
    __syncthreads();

    // ---- score: add rel-shifted position (LDS gather), scale, masks
    const int q = q0 + c;
    const float padq = spad[q];
    float mx = -3.0e38f;
    #pragma unroll
    for (int m = 0; m < 16; ++m) {
        int k0e = kbase + m * 16 + g * 4;
        uint_t mb[4];
        if (mm == 1) {
            uint_t w = *(const uint_t*)((const uchar_t*)mask + (size_t)q * 1024 + k0e);
            mb[0] = w & 0xFFu; mb[1] = w & 0xFF00u; mb[2] = w & 0xFF0000u; mb[3] = w & 0xFF000000u;
        } else if (mm == 2) {
            uint2 w = *(const uint2*)((const ushort_t*)mask + (size_t)q * 1024 + k0e);
            mb[0] = w.x & 0xFFFFu; mb[1] = w.x >> 16; mb[2] = w.y & 0xFFFFu; mb[3] = w.y >> 16;
        } else {
            uint4 w = *(const uint4*)((const uint_t*)mask + (size_t)q * 1024 + k0e);
            mb[0] = w.x; mb[1] = w.y; mb[2] = w.z; mb[3] = w.w;
        }
        #pragma unroll
        for (int jj = 0; jj < 4; ++jj) {
            int k = k0e + jj;
            int delta = k - q;
            int wrap = (delta > 512) ? 1 : 0;
            int j = wrap ? (delta - 514) : (delta + 511);
            float pos = b2f(sPRu[(c + wrap) * 1040 + (j < 0 ? 0 : j)]);
            if (delta == 513) pos = 0.f;
            float s = (acc[m][jj] + pos) * 0.03125f;
            bool dead = (mb[jj] != 0);
            if (k >= 512) {
                float padk = spad[k - 512];
                if (padq == 0.f || padk == 0.f) dead = true;
            }
            if (dead) s = -1e20f;
            acc[m][jj] = s;
            mx = fmaxf(mx, s);
        }
    }
    // row-max: lanes sharing q are xor-16/32 apart
    mx = fmaxf(mx, __shfl_xor(mx, 16, 64));
    mx = fmaxf(mx, __shfl_xor(mx, 32, 64));
    if (lane < 16) sred[0][wid][c] = mx;
    __syncthreads();
    mx = fmaxf(fmaxf(sred[0][0][c], sred[0][1][c]), fmaxf(sred[0][2][c], sred[0][3][c]));

    float ls = 0.f;
    #pragma unroll
    for (int m = 0; m < 16; ++m) {
        #pragma unroll
        for (int jj = 0; jj < 4; ++jj) {
            float p = __expf(acc[m][jj] - mx);
            acc[m][jj] = p;
            ls += p;
        }
    }
    ls += __shfl_xor(ls, 16, 64);
    ls += __shfl_xor(ls, 32, 64);
    if (lane < 16) sred[1][wid][c] = ls;
    __syncthreads();
    ls = (sred[1][0][c] + sred[1][1][c]) + (sred[1][2][c] + sred[1][3][c]);
    if (wid == 0 && lane < 16) ssinv[c] = 1.0f / ls;

    // ---- PV: O^T[d][q] = sum_k V^T[d][k] P^T[k][q], MFMA with in-register P exchange
    f32x4 oacc[4];
    #pragma unroll
    for (int dm = 0; dm < 4; ++dm) oacc[dm] = (f32x4){0.f, 0.f, 0.f, 0.f};
    const int srcA = c + ((g & 1) ? 32 : 0);
    const int srcB = srcA + 16;
    #pragma unroll
    for (int ch = 0; ch < 8; ++ch) {
        const int mA = ch * 2, mB = mA + 1;
        uint_t u00 = pk2(acc[mA][0], acc[mA][1]);
        uint_t u10 = pk2(acc[mA][2], acc[mA][3]);
        uint_t u01 = pk2(acc[mB][0], acc[mB][1]);
        uint_t u11 = pk2(acc[mB][2], acc[mB][3]);
        uint_t r0 = (uint_t)__shfl((int)u00, srcA, 64);
        uint_t r1 = (uint_t)__shfl((int)u10, srcA, 64);
        uint_t r2 = (uint_t)__shfl((int)u00, srcB, 64);
        uint_t r3 = (uint_t)__shfl((int)u10, srcB, 64);
        uint_t s0 = (uint_t)__shfl((int)u01, srcA, 64);
        uint_t s1 = (uint_t)__shfl((int)u11, srcA, 64);
        uint_t s2 = (uint_t)__shfl((int)u01, srcB, 64);
        uint_t s3 = (uint_t)__shfl((int)u11, srcB, 64);
        union { uint_t u[4]; short8 s8; } pb;
        bool lo = (g < 2);
        pb.u[0] = lo ? r0 : s0;
        pb.u[1] = lo ? r1 : s1;
        pb.u[2] = lo ? r2 : s2;
        pb.u[3] = lo ? r3 : s3;
        #pragma unroll
        for (int dm = 0; dm < 4; ++dm) {
            const ushort_t* vp = vT + ((size_t)bh * 64 + dm * 16 + c) * 1024 + kbase + ch * 32 + g * 8;
            short8 va = *(const short8*)vp;
            oacc[dm] = MFMA16(va, pb.s8, oacc[dm]);
        }
    }

    // cross-wave O reduction (reuse sPRu region; all PR reads completed pre-barrier)
    float* sO = (float*)sPRu;
    #pragma unroll
    for (int dm = 0; dm < 4; ++dm)
        #pragma unroll
        for (int jj = 0; jj < 4; ++jj)
            sO[wid * 1152 + (dm * 16 + g * 4 + jj) * 18 + c] = oacc[dm][jj];
    __syncthreads();
    for (int e = tid; e < 1024; e += 256) {
        int d = e & 63, qq = e >> 6;
        float v = (sO[d * 18 + qq] + sO[1152 + d * 18 + qq]) +
                  (sO[2304 + d * 18 + qq] + sO[3456 + d * 18 + qq]);
        v *= ssinv[qq];
        alpha[((size_t)(q0 + qq) * 8 + b) * 1024 + h * 64 + d] = f2b(v);
    }
}

// ---------------- launcher (EXACT round-3 layout) ----------------
extern "C" void kernel_launch(void* const* d_in, const int* in_sizes, int n_in,
                              void* d_out, int out_size, void* d_ws, size_t ws_size,
                              hipStream_t stream) {
    char* ws = (char*)d_ws;
    int* flags = (int*)ws;
    ushort_t* WqT   = (ushort_t*)(ws + 1024);
    ushort_t* WkT   = WqT + 1048576;
    ushort_t* WvT   = WkT + 1048576;
    ushort_t* WposT = WvT + 1048576;
    ushort_t* WoT   = WposT + 1048576;
    ushort_t* qUw   = WoT + 1048576;
    ushort_t* qVw   = qUw + 4194304;
    ushort_t* khw   = qVw + 4194304;
    ushort_t* vhw   = khw + 8388608;
    ushort_t* vTw   = vhw + 8388608;
    ushort_t* Rlw   = vTw + 8388608;
    ushort_t* alw   = Rlw + 1048576;

    detect_kernel<<<1, 256, 0, stream>>>(d_in[6], d_in[7], flags);
    transpose_kernel<<<dim3(32, 32, 5), dim3(32, 8), 0, stream>>>(
        d_in[8], d_in[10], d_in[12], d_in[14], d_in[15],
        WqT, WkT, WvT, WposT, WoT, flags);
    // q projection -> qU, qV
    gemm_kernel<0><<<dim3(32, 8), 256, 0, stream>>>(d_in[0], WqT, 4096, d_in[9], d_in[4], d_in[5], qUw, qVw, flags, 1);
    // k, v projections
    gemm_kernel<1><<<dim3(64, 8), 256, 0, stream>>>(d_in[1], WkT, 8192, d_in[11], nullptr, nullptr, khw, nullptr, flags, 1);
    gemm_kernel<1><<<dim3(64, 8), 256, 0, stream>>>(d_in[2], WvT, 8192, d_in[13], nullptr, nullptr, vhw, nullptr, flags, 1);
    // R projection
    gemm_kernel<2><<<dim3(8, 8), 256, 0, stream>>>(d_in[3], WposT, 1024, nullptr, nullptr, nullptr, Rlw, nullptr, flags, 1);
    // V transpose for PV A-operand
    vtrans_kernel<<<dim3(16, 128), 256, 0, stream>>>(vhw, vTw);
    // fused attention
    attn_kernel<<<dim3(32, 128), 256, 0, stream>>>(qUw, qVw, khw, vTw, Rlw, d_in[6], d_in[7], alw, flags);
    // output projection
    gemm_kernel<3><<<dim3(32, 8), 256, 0, stream>>>(alw, WoT, 4096, d_in[16], nullptr, nullptr, d_out, nullptr, flags, 0);
}

// Round 7
// 434.203 us; speedup vs baseline: 1.7557x; 1.1123x over previous
//
#include <hip/hip_runtime.h>

#define QLEN 512
#define KLEN 1024
#define BATCH 8
#define HEADS 16
#define HDIM 64
#define EMBED 1024

typedef __attribute__((ext_vector_type(4))) float f32x4;
typedef __attribute__((ext_vector_type(8))) short short8;
typedef unsigned short ushort_t;
typedef unsigned char uchar_t;
typedef unsigned int uint_t;

#define MFMA16(a, b, c) __builtin_amdgcn_mfma_f32_16x16x32_bf16((a), (b), (c), 0, 0, 0)

__device__ __forceinline__ float b2f(ushort_t u) {
    union { uint_t i; float f; } c; c.i = ((uint_t)u) << 16; return c.f;
}
__device__ __forceinline__ ushort_t f2b(float x) {
    union { float f; uint_t i; } c; c.f = x;
    uint_t u = c.i;
    uint_t r = (u + 0x7FFFu + ((u >> 16) & 1u)) >> 16;
    return (ushort_t)r;
}
__device__ __forceinline__ uint_t pk2(float lo, float hi) {
    return (uint_t)f2b(lo) | ((uint_t)f2b(hi) << 16);
}
// load a "float" that may be stored as f32 or bf16
__device__ __forceinline__ float ldf(const void* p, int idx, int f32m) {
    if (f32m) return ((const float*)p)[idx];
    return b2f(((const ushort_t*)p)[idx]);
}

typedef const __attribute__((address_space(1))) void async_src_t;
typedef __attribute__((address_space(3))) void async_dst_t;

// ---------------- dtype detector ----------------
// flags[0]: 1 if float tensors are f32, 0 if bf16
// flags[1]: mask mode: 0=int32, 1=uint8, 2=bf16, 3=f32
__global__ __launch_bounds__(256) void detect_kernel(const void* mask, const void* pad, int* flags) {
    __shared__ int cnt[4];
    int tid = threadIdx.x;
    if (tid < 4) cnt[tid] = 0;
    __syncthreads();
    const uchar_t* mb = (const uchar_t*)mask;
    const uchar_t* pb = (const uchar_t*)pad;
    int lnz1 = 0, l3f1 = 0, l3f3 = 0, lpnz = 0;
    for (int off = tid; off < 4096; off += 256) {
        uchar_t v = mb[off];
        int m4 = off & 3;
        if (m4 != 0 && v != 0) lnz1++;
        if (m4 == 1 && v == 0x3F) l3f1++;
        if (m4 == 3 && v == 0x3F) l3f3++;
        uchar_t p = pb[off];
        if (m4 == 0 && p != 0) lpnz++;
    }
    atomicAdd(&cnt[0], lnz1); atomicAdd(&cnt[1], l3f1);
    atomicAdd(&cnt[2], l3f3); atomicAdd(&cnt[3], lpnz);
    __syncthreads();
    if (tid == 0) {
        flags[0] = (cnt[3] == 0) ? 1 : 0;
        int mm;
        if (cnt[0] == 0) mm = 0;
        else if (cnt[1] > 16) mm = 2;
        else if (cnt[2] > 16) mm = 3;
        else mm = 1;
        flags[1] = mm;
    }
}

// ---------------- bulk convert to bf16 (pk2-based, no inline asm) ----------------
__global__ __launch_bounds__(256) void convert_kernel(const void* __restrict__ src,
                                                      ushort_t* __restrict__ dst,
                                                      int n8, const int* flags) {
    int i = blockIdx.x * 256 + threadIdx.x;
    if (i >= n8) return;
    if (flags[0]) {
        const float4* s = (const float4*)src + (size_t)i * 2;
        float4 a = s[0], b = s[1];
        uint4 o;
        o.x = pk2(a.x, a.y); o.y = pk2(a.z, a.w);
        o.z = pk2(b.x, b.y); o.w = pk2(b.z, b.w);
        ((uint4*)dst)[i] = o;
    } else {
        ((uint4*)dst)[i] = ((const uint4*)src)[i];
    }
}

// ---------------- weight transpose (to bf16 W^T) ----------------
__global__ __launch_bounds__(256) void transpose_kernel(
    const void* W0, const void* W1, const void* W2, const void* W3, const void* W4,
    ushort_t* T0, ushort_t* T1, ushort_t* T2, ushort_t* T3, ushort_t* T4,
    const int* flags) {
    __shared__ float tl[32][33];
    int f32m = flags[0];
    const void* W; ushort_t* T;
    switch (blockIdx.z) {
        case 0: W = W0; T = T0; break;
        case 1: W = W1; T = T1; break;
        case 2: W = W2; T = T2; break;
        case 3: W = W3; T = T3; break;
        default: W = W4; T = T4; break;
    }
    int tx = threadIdx.x, ty = threadIdx.y;  // (32,8)
    int x = blockIdx.x * 32 + tx;
    #pragma unroll
    for (int j = 0; j < 4; ++j) {
        int row = blockIdx.y * 32 + ty + j * 8;
        tl[ty + j * 8][tx] = ldf(W, row * 1024 + x, f32m);
    }
    __syncthreads();
    #pragma unroll
    for (int j = 0; j < 4; ++j) {
        int n = blockIdx.x * 32 + ty + j * 8;
        T[n * 1024 + blockIdx.y * 32 + tx] = f2b(tl[tx][ty + j * 8]);
    }
}

// ---------------- V transpose: vh[bh][k][d] -> vT[bh][d][k] ----------------
__global__ __launch_bounds__(256) void vtrans_kernel(const ushort_t* __restrict__ vh,
                                                     ushort_t* __restrict__ vT) {
    __shared__ ushort_t t[64][68];
    int bh = blockIdx.y;
    int k0 = blockIdx.x * 64;
    int tid = threadIdx.x;
    int r = tid >> 2, c0 = (tid & 3) * 16;
    const short8* src = (const short8*)&vh[((size_t)bh * 1024 + k0 + r) * 64 + c0];
    *(short8*)&t[r][c0] = src[0];
    *(short8*)&t[r][c0 + 8] = src[1];
    __syncthreads();
    ushort_t tmp[16];
    #pragma unroll
    for (int j = 0; j < 16; ++j) tmp[j] = t[c0 + j][r];
    short8* dst = (short8*)&vT[((size_t)bh * 64 + r) * 1024 + k0 + c0];
    dst[0] = *(short8*)&tmp[0];
    dst[1] = *(short8*)&tmp[8];
}

// ---------------- projection GEMM (global_load_lds, linear LDS) ----------------
// EPI 0: qU/qV (adds bq then U/V, layout (b,h,q,d))
// EPI 1: k/v proj (adds bias, layout (b,h,kk,d))
// EPI 2: R proj (no bias, layout (h,j,d));  a_mode=1: A may be f32 (scalar staging)
// EPI 3: out proj (adds bias, writes d_out (q,b,e), dtype per flag)
template<int EPI>
__global__ __launch_bounds__(256) void gemm_kernel(
    const void* Av, const ushort_t* BT, int M,
    const void* bias, const void* Up, const void* Vp,
    void* out0, void* out1, const int* flags, int a_mode) {
    __shared__ ushort_t As[4096];
    __shared__ ushort_t Bs[4096];
    const int f32m = flags[0];
    const int a_f32 = a_mode ? f32m : 0;
    const int tid = threadIdx.x;
    const int wid = tid >> 6, lane = tid & 63;
    const int wr = (wid >> 1) * 64, wc = (wid & 1) * 64;
    const int m0 = blockIdx.x * 128, n0 = blockIdx.y * 128;
    const int ch0 = wid * 2;
    const int lrow = lane >> 2, lcol = (lane & 3) * 8;

    f32x4 acc[4][4];
    #pragma unroll
    for (int m = 0; m < 4; ++m)
        #pragma unroll
        for (int n = 0; n < 4; ++n)
            acc[m][n] = (f32x4){0.f, 0.f, 0.f, 0.f};

    for (int k0 = 0; k0 < 1024; k0 += 32) {
        if (a_f32) {
            const float* Af = (const float*)Av + (size_t)(m0 + (tid >> 1)) * 1024 + k0 + (tid & 1) * 16;
            ushort_t* dst = &As[(tid >> 1) * 32 + (tid & 1) * 16];
            #pragma unroll
            for (int e = 0; e < 16; ++e) dst[e] = f2b(Af[e]);
        } else {
            #pragma unroll
            for (int t = 0; t < 2; ++t) {
                int ch = ch0 + t;
                const ushort_t* ga = (const ushort_t*)Av + (size_t)(m0 + ch * 16 + lrow) * 1024 + k0 + lcol;
                __builtin_amdgcn_global_load_lds((async_src_t*)ga, (async_dst_t*)&As[ch * 512], 16, 0, 0);
            }
        }
        #pragma unroll
        for (int t = 0; t < 2; ++t) {
            int ch = ch0 + t;
            const ushort_t* gb = BT + (size_t)(n0 + ch * 16 + lrow) * 1024 + k0 + lcol;
            __builtin_amdgcn_global_load_lds((async_src_t*)gb, (async_dst_t*)&Bs[ch * 512], 16, 0, 0);
        }
        __syncthreads();

        short8 af[4], bf[4];
        #pragma unroll
        for (int m = 0; m < 4; ++m)
            af[m] = *(const short8*)&As[(wr + m * 16 + (lane & 15)) * 32 + (lane >> 4) * 8];
        #pragma unroll
        for (int n = 0; n < 4; ++n)
            bf[n] = *(const short8*)&Bs[(wc + n * 16 + (lane & 15)) * 32 + (lane >> 4) * 8];
        #pragma unroll
        for (int m = 0; m < 4; ++m)
            #pragma unroll
            for (int n = 0; n < 4; ++n)
                acc[m][n] = MFMA16(af[m], bf[n], acc[m][n]);
        __syncthreads();
    }

    #pragma unroll
    for (int n = 0; n < 4; ++n) {
        int gn = n0 + wc + n * 16 + (lane & 15);
        float bv_ = (EPI == 2) ? 0.f : ldf(bias, gn, f32m);
        float uu = 0.f, vv = 0.f;
        if (EPI == 0) { uu = ldf(Up, gn, f32m); vv = ldf(Vp, gn, f32m); }
        #pragma unroll
        for (int m = 0; m < 4; ++m) {
            #pragma unroll
            for (int j = 0; j < 4; ++j) {
                int gm = m0 + wr + m * 16 + (lane >> 4) * 4 + j;
                float c = acc[m][n][j] + bv_;
                if (EPI == 0) {
                    int q = gm >> 3, b = gm & 7;
                    int h = gn >> 6, d = gn & 63;
                    int idx = ((b * 16 + h) * 512 + q) * 64 + d;
                    ((ushort_t*)out0)[idx] = f2b(c + uu);
                    ((ushort_t*)out1)[idx] = f2b(c + vv);
                } else if (EPI == 1) {
                    int kk = gm >> 3, b = gm & 7;
                    int h = gn >> 6, d = gn & 63;
                    ((ushort_t*)out0)[((b * 16 + h) * 1024 + kk) * 64 + d] = f2b(c);
                } else if (EPI == 2) {
                    int h = gn >> 6, d = gn & 63;
                    ((ushort_t*)out0)[(h * 1024 + gm) * 64 + d] = f2b(c);
                } else {
                    if (f32m) ((float*)out0)[gm * 1024 + gn] = c;
                    else ((ushort_t*)out0)[gm * 1024 + gn] = f2b(c);
                }
            }
        }
    }
}

// ---------------- fused attention (S^T layout, MFMA PV, bf16 PR, 8 waves) ----------------
// block: 16 q-rows x one (b,h); 8 waves, wave w owns k in [w*128, w*128+128)
// Lane: c = lane&15 = q-column, g = lane>>4. S^T C-layout: col=c(q), row=k-local.
__global__ __launch_bounds__(512, 4) void attn_kernel(
    const ushort_t* __restrict__ qU, const ushort_t* __restrict__ qV,
    const ushort_t* __restrict__ kh, const ushort_t* __restrict__ vT,
    const ushort_t* __restrict__ Rl, const void* __restrict__ mask,
    const void* __restrict__ pad, ushort_t* __restrict__ alpha, const int* flags) {

    __shared__ __align__(16) ushort_t sPRu[17 * 1040];   // PR rows q0..q0+16, bf16, stride 1040
    __shared__ float spad[512];
    __shared__ float sred[2][8][16];
    __shared__ float ssinv[16];

    const int tid = threadIdx.x;
    const int wid = tid >> 6, lane = tid & 63;
    const int g = lane >> 4, c = lane & 15;
    const int q0 = blockIdx.x * 16;
    const int bh = blockIdx.y;
    const int b = bh >> 4, h = bh & 15;
    const int f32m = flags[0], mm = flags[1];
    const int kbase = wid * 128;

    if (tid < 512) spad[tid] = ldf(pad, b * 512 + tid, f32m);

    // ---- position: PR^T[j][q] = R[j] . qV[q];  write PR[q][j] (bf16) to LDS
    {
        const ushort_t* qvap = qV + ((size_t)bh * 512 + q0 + c) * 64 + g * 8;
        short8 bva0 = *(const short8*)qvap;
        short8 bva1 = *(const short8*)(qvap + 32);
        int qvbq = q0 + 16 + c; if (qvbq > 511) qvbq = 511;
        const ushort_t* qvbp = qV + ((size_t)bh * 512 + qvbq) * 64 + g * 8;
        short8 bvb0 = *(const short8*)qvbp;
        short8 bvb1 = *(const short8*)(qvbp + 32);
        #pragma unroll
        for (int m = 0; m < 8; ++m) {
            const ushort_t* rp = Rl + ((size_t)h * 1024 + kbase + m * 16 + c) * 64 + g * 8;
            short8 ra0 = *(const short8*)rp;
            short8 ra1 = *(const short8*)(rp + 32);
            f32x4 p0 = (f32x4){0.f, 0.f, 0.f, 0.f};
            p0 = MFMA16(ra0, bva0, p0);
            p0 = MFMA16(ra1, bva1, p0);
            f32x4 p1 = (f32x4){0.f, 0.f, 0.f, 0.f};
            p1 = MFMA16(ra0, bvb0, p1);
            p1 = MFMA16(ra1, bvb1, p1);
            uint2 w;
            w.x = pk2(p0[0], p0[1]);
            w.y = pk2(p0[2], p0[3]);
            *(uint2*)&sPRu[c * 1040 + kbase + m * 16 + g * 4] = w;
            if (c == 0) {
                uint2 x;
                x.x = pk2(p1[0], p1[1]);
                x.y = pk2(p1[2], p1[3]);
                *(uint2*)&sPRu[16 * 1040 + kbase + m * 16 + g * 4] = x;
            }
        }
    }

    // ---- content: S^T[k][q] = K[k] . qU[q]
    f32x4 acc[8];
    {
        const ushort_t* qup = qU + ((size_t)bh * 512 + q0 + c) * 64 + g * 8;
        short8 bu0 = *(const short8*)qup;
        short8 bu1 = *(const short8*)(qup + 32);
        #pragma unroll
        for (int m = 0; m < 8; ++m) {
            const ushort_t* kp = kh + ((size_t)bh * 1024 + kbase + m * 16 + c) * 64 + g * 8;
            short8 ka0 = *(const short8*)kp;
            short8 ka1 = *(const short8*)(kp + 32);
            f32x4 t = (f32x4){0.f, 0.f, 0.f, 0.f};
            t = MFMA16(ka0, bu0, t);
            t = MFMA16(ka1, bu1, t);
            acc[m] = t;
        }
    }
    __syncthreads();

    // ---- score: add rel-shifted position (LDS gather), scale, masks
    const int q = q0 + c;
    const float padq = spad[q];
    float mx = -3.0e38f;
    #pragma unroll
    for (int m = 0; m < 8; ++m) {
        int k0e = kbase + m * 16 + g * 4;
        uint_t mb[4];
        if (mm == 1) {
            uint_t w = *(const uint_t*)((const uchar_t*)mask + (size_t)q * 1024 + k0e);
            mb[0] = w & 0xFFu; mb[1] = w & 0xFF00u; mb[2] = w & 0xFF0000u; mb[3] = w & 0xFF000000u;
        } else if (mm == 2) {
            uint2 w = *(const uint2*)((const ushort_t*)mask + (size_t)q * 1024 + k0e);
            mb[0] = w.x & 0xFFFFu; mb[1] = w.x >> 16; mb[2] = w.y & 0xFFFFu; mb[3] = w.y >> 16;
        } else {
            uint4 w = *(const uint4*)((const uint_t*)mask + (size_t)q * 1024 + k0e);
            mb[0] = w.x; mb[1] = w.y; mb[2] = w.z; mb[3] = w.w;
        }
        #pragma unroll
        for (int jj = 0; jj < 4; ++jj) {
            int k = k0e + jj;
            int delta = k - q;
            int wrap = (delta > 512) ? 1 : 0;
            int j = wrap ? (delta - 514) : (delta + 511);
            float pos = b2f(sPRu[(c + wrap) * 1040 + (j < 0 ? 0 : j)]);
            if (delta == 513) pos = 0.f;
            float s = (acc[m][jj] + pos) * 0.03125f;
            bool dead = (mb[jj] != 0);
            if (k >= 512) {
                float padk = spad[k - 512];
                if (padq == 0.f || padk == 0.f) dead = true;
            }
            if (dead) s = -1e20f;
            acc[m][jj] = s;
            mx = fmaxf(mx, s);
        }
    }
    // row-max: lanes sharing q are xor-16/32 apart; then cross-wave
    mx = fmaxf(mx, __shfl_xor(mx, 16, 64));
    mx = fmaxf(mx, __shfl_xor(mx, 32, 64));
    if (lane < 16) sred[0][wid][c] = mx;
    __syncthreads();
    {
        float a0 = fmaxf(fmaxf(sred[0][0][c], sred[0][1][c]), fmaxf(sred[0][2][c], sred[0][3][c]));
        float a1 = fmaxf(fmaxf(sred[0][4][c], sred[0][5][c]), fmaxf(sred[0][6][c], sred[0][7][c]));
        mx = fmaxf(a0, a1);
    }

    float ls = 0.f;
    #pragma unroll
    for (int m = 0; m < 8; ++m) {
        #pragma unroll
        for (int jj = 0; jj < 4; ++jj) {
            float p = __expf(acc[m][jj] - mx);
            acc[m][jj] = p;
            ls += p;
        }
    }
    ls += __shfl_xor(ls, 16, 64);
    ls += __shfl_xor(ls, 32, 64);
    if (lane < 16) sred[1][wid][c] = ls;
    __syncthreads();
    {
        float a0 = (sred[1][0][c] + sred[1][1][c]) + (sred[1][2][c] + sred[1][3][c]);
        float a1 = (sred[1][4][c] + sred[1][5][c]) + (sred[1][6][c] + sred[1][7][c]);
        ls = a0 + a1;
    }
    if (wid == 0 && lane < 16) ssinv[c] = 1.0f / ls;

    // ---- PV: O^T[d][q] = sum_k V^T[d][k] P^T[k][q], MFMA with in-register P exchange
    f32x4 oacc[4];
    #pragma unroll
    for (int dm = 0; dm < 4; ++dm) oacc[dm] = (f32x4){0.f, 0.f, 0.f, 0.f};
    const int srcA = c + ((g & 1) ? 32 : 0);
    const int srcB = srcA + 16;
    #pragma unroll
    for (int ch = 0; ch < 4; ++ch) {
        const int mA = ch * 2, mB = mA + 1;
        uint_t u00 = pk2(acc[mA][0], acc[mA][1]);
        uint_t u10 = pk2(acc[mA][2], acc[mA][3]);
        uint_t u01 = pk2(acc[mB][0], acc[mB][1]);
        uint_t u11 = pk2(acc[mB][2], acc[mB][3]);
        uint_t r0 = (uint_t)__shfl((int)u00, srcA, 64);
        uint_t r1 = (uint_t)__shfl((int)u10, srcA, 64);
        uint_t r2 = (uint_t)__shfl((int)u00, srcB, 64);
        uint_t r3 = (uint_t)__shfl((int)u10, srcB, 64);
        uint_t s0 = (uint_t)__shfl((int)u01, srcA, 64);
        uint_t s1 = (uint_t)__shfl((int)u11, srcA, 64);
        uint_t s2 = (uint_t)__shfl((int)u01, srcB, 64);
        uint_t s3 = (uint_t)__shfl((int)u11, srcB, 64);
        union { uint_t u[4]; short8 s8; } pb;
        bool lo = (g < 2);
        pb.u[0] = lo ? r0 : s0;
        pb.u[1] = lo ? r1 : s1;
        pb.u[2] = lo ? r2 : s2;
        pb.u[3] = lo ? r3 : s3;
        #pragma unroll
        for (int dm = 0; dm < 4; ++dm) {
            const ushort_t* vp = vT + ((size_t)bh * 64 + dm * 16 + c) * 1024 + kbase + ch * 32 + g * 8;
            short8 va = *(const short8*)vp;
            oacc[dm] = MFMA16(va, pb.s8, oacc[dm]);
        }
    }

    // cross-wave O reduction (reuse sPRu region; all PR reads completed pre-barrier)
    float* sO = (float*)sPRu;
    #pragma unroll
    for (int dm = 0; dm < 4; ++dm)
        #pragma unroll
        for (int jj = 0; jj < 4; ++jj)
            sO[wid * 1088 + (dm * 16 + g * 4 + jj) * 17 + c] = oacc[dm][jj];
    __syncthreads();
    for (int e = tid; e < 1024; e += 512) {
        int d = e & 63, qq = e >> 6;
        float v = ((sO[d * 17 + qq] + sO[1088 + d * 17 + qq]) +
                   (sO[2176 + d * 17 + qq] + sO[3264 + d * 17 + qq])) +
                  ((sO[4352 + d * 17 + qq] + sO[5440 + d * 17 + qq]) +
                   (sO[6528 + d * 17 + qq] + sO[7616 + d * 17 + qq]));
        v *= ssinv[qq];
        alpha[((size_t)(q0 + qq) * 8 + b) * 1024 + h * 64 + d] = f2b(v);
    }
}

// ---------------- launcher ----------------
// Workspace: EXACTLY 88,081,408 bytes (round-3/6 proven footprint), r5 alias scheme.
extern "C" void kernel_launch(void* const* d_in, const int* in_sizes, int n_in,
                              void* d_out, int out_size, void* d_ws, size_t ws_size,
                              hipStream_t stream) {
    char* ws = (char*)d_ws;
    int* flags = (int*)ws;
    ushort_t* WqT   = (ushort_t*)(ws + 1024);
    ushort_t* WkT   = WqT + 1048576;
    ushort_t* WvT   = WkT + 1048576;
    ushort_t* WposT = WvT + 1048576;
    ushort_t* WoT   = WposT + 1048576;
    ushort_t* qUw   = WoT + 1048576;            // 4,194,304
    ushort_t* qVw   = qUw + 4194304;            // 4,194,304
    ushort_t* khw   = qVw + 4194304;            // 8,388,608
    ushort_t* Rlw   = khw + 8388608;            // 1,048,576
    ushort_t* R1    = Rlw + 1048576;            // 4,194,304
    ushort_t* R2    = R1 + 4194304;             // 8,388,608
    ushort_t* R3    = R2 + 8388608;             // 8,388,608
    // aliases (lifetime-disjoint, stream-ordered):
    ushort_t* qbf = R1;     // convert out -> read by qGEMM -> dead
    ushort_t* alw = R1;     // attn out -> read by outGEMM
    ushort_t* kbf = R2;     // convert out -> read by kGEMM -> dead
    ushort_t* vhw = R2;     // vGEMM out -> read by vtrans -> dead
    ushort_t* vbf = R3;     // convert out -> read by vGEMM -> dead
    ushort_t* vTw = R3;     // vtrans out -> read by attn

    detect_kernel<<<1, 256, 0, stream>>>(d_in[6], d_in[7], flags);
    // bulk input conversion to bf16 (query, key, value)
    convert_kernel<<<2048, 256, 0, stream>>>(d_in[0], qbf, 524288, flags);
    convert_kernel<<<4096, 256, 0, stream>>>(d_in[1], kbf, 1048576, flags);
    convert_kernel<<<4096, 256, 0, stream>>>(d_in[2], vbf, 1048576, flags);
    // weight transposes
    transpose_kernel<<<dim3(32, 32, 5), dim3(32, 8), 0, stream>>>(
        d_in[8], d_in[10], d_in[12], d_in[14], d_in[15],
        WqT, WkT, WvT, WposT, WoT, flags);
    // q projection -> qU, qV (fast A path)
    gemm_kernel<0><<<dim3(32, 8), 256, 0, stream>>>(qbf, WqT, 4096, d_in[9], d_in[4], d_in[5], qUw, qVw, flags, 0);
    // k, v projections (fast A path)
    gemm_kernel<1><<<dim3(64, 8), 256, 0, stream>>>(kbf, WkT, 8192, d_in[11], nullptr, nullptr, khw, nullptr, flags, 0);
    gemm_kernel<1><<<dim3(64, 8), 256, 0, stream>>>(vbf, WvT, 8192, d_in[13], nullptr, nullptr, vhw, nullptr, flags, 0);
    // R projection (raw pos_embedding, scalar-convert staging when f32)
    gemm_kernel<2><<<dim3(8, 8), 256, 0, stream>>>(d_in[3], WposT, 1024, nullptr, nullptr, nullptr, Rlw, nullptr, flags, 1);
    // V transpose for PV A-operand: R2 -> R3
    vtrans_kernel<<<dim3(16, 128), 256, 0, stream>>>(vhw, vTw);
    // fused attention (8 waves/block)
    attn_kernel<<<dim3(32, 128), 512, 0, stream>>>(qUw, qVw, khw, vTw, Rlw, d_in[6], d_in[7], alw, flags);
    // output projection
    gemm_kernel<3><<<dim3(32, 8), 256, 0, stream>>>(alw, WoT, 4096, d_in[16], nullptr, nullptr, d_out, nullptr, flags, 0);
}